// Round 3
// baseline (1429.159 us; speedup 1.0000x reference)
//
#include <hip/hip_runtime.h>
#include <hip/hip_bf16.h>

#define B_   8
#define TQ_  8
#define TP_  447
#define TC_  1500
#define D_   1280
#define H_   20
#define DH_  64
#define DFF_ 5120
#define M_   64    // B_*TQ_ total rows

// ================= LayerNorm: row-major fp32 input -> transposed f32 [D_][M_]
__global__ __launch_bounds__(256) void ln_kernel(const float* __restrict__ X,
    const float* __restrict__ g, const float* __restrict__ be, float* __restrict__ outT)
{
  __shared__ float redA[4], redB[4];
  const int m = blockIdx.x;
  const int tid = threadIdx.x;
  float v[5];
#pragma unroll
  for (int t = 0; t < 5; ++t) v[t] = X[(size_t)m*D_ + tid + t*256];
  float s = v[0]+v[1]+v[2]+v[3]+v[4];
#pragma unroll
  for (int o = 32; o; o >>= 1) s += __shfl_down(s, o, 64);
  if ((tid & 63) == 0) redA[tid >> 6] = s;
  __syncthreads();
  const float mean = (redA[0]+redA[1]+redA[2]+redA[3]) * (1.0f/D_);
  float q = 0.f;
#pragma unroll
  for (int t = 0; t < 5; ++t) { const float d = v[t]-mean; q += d*d; }
#pragma unroll
  for (int o = 32; o; o >>= 1) q += __shfl_down(q, o, 64);
  if ((tid & 63) == 0) redB[tid >> 6] = q;
  __syncthreads();
  const float rstd = rsqrtf((redB[0]+redB[1]+redB[2]+redB[3]) * (1.0f/D_) + 1e-5f);
#pragma unroll
  for (int t = 0; t < 5; ++t) {
    const int c = tid + t*256;
    outT[(size_t)c*M_ + m] = (v[t]-mean)*rstd*g[c] + be[c];
  }
}

// ================= split-K GEMM: P[s][m][n] = sum_{k in chunk s} XT[k][m]*W[k][n]
// XT: [K][M_] f32. W: [K][N] f32 row-major. grid (N/128, S, nz), block 256.
// Wave wv owns rows wv*16..+16; lane owns 2 cols. X staged via LDS in 64-k slabs.
__global__ __launch_bounds__(256) void gemm_splitk(
    const float* __restrict__ XT,
    const float* __restrict__ Wa, const float* __restrict__ Wb, const float* __restrict__ Wc,
    float* __restrict__ Pa, float* __restrict__ Pb, float* __restrict__ Pc,
    int N, int chunk)
{
  __shared__ float xs[64][64];
  const int z = blockIdx.z;
  const float* W = (z == 0 ? Wa : (z == 1 ? Wb : Wc));
  float* P = (z == 0 ? Pa : (z == 1 ? Pb : Pc));
  const int tid  = threadIdx.x;
  const int lane = tid & 63;
  const int wv   = tid >> 6;
  const int n    = blockIdx.x*128 + lane*2;
  const int k0   = blockIdx.y * chunk;
  float accL[16], accH[16];
#pragma unroll
  for (int r = 0; r < 16; ++r) { accL[r] = 0.f; accH[r] = 0.f; }

  for (int kb = 0; kb < chunk; kb += 64) {
    __syncthreads();
    {
      const float4* src = (const float4*)(XT + (size_t)(k0 + kb)*M_);
      float4* dst = (float4*)&xs[0][0];
#pragma unroll
      for (int i = 0; i < 4; ++i) dst[tid + i*256] = src[tid + i*256];
    }
    __syncthreads();
    const float* Wp = W + (size_t)(k0 + kb)*N + n;
    for (int kk = 0; kk < 64; ++kk) {
      const float2 wp = *(const float2*)(Wp + (size_t)kk*N);
      const float wl = wp.x;
      const float wh = wp.y;
      const float* xr = &xs[kk][wv*16];
#pragma unroll
      for (int r4 = 0; r4 < 4; ++r4) {
        const float4 xv = *(const float4*)(xr + r4*4);
        accL[r4*4+0] += xv.x*wl; accH[r4*4+0] += xv.x*wh;
        accL[r4*4+1] += xv.y*wl; accH[r4*4+1] += xv.y*wh;
        accL[r4*4+2] += xv.z*wl; accH[r4*4+2] += xv.z*wh;
        accL[r4*4+3] += xv.w*wl; accH[r4*4+3] += xv.w*wh;
      }
    }
  }
#pragma unroll
  for (int r = 0; r < 16; ++r) {
    const int m = wv*16 + r;
    float2 st; st.x = accL[r]; st.y = accH[r];
    *(float2*)(P + ((size_t)blockIdx.y*M_ + m)*N + n) = st;
  }
}

// ================= epilogue: sum split-K partials, +bias, gelu, +residual, multi-format out
__global__ __launch_bounds__(256) void epilogue_kernel(
    const float* __restrict__ P, int S, int N,
    const float* __restrict__ bias,
    const float* __restrict__ res,
    int gelu,
    float* __restrict__ outA, float* __restrict__ outT, float* __restrict__ outB)
{
  const int idx = blockIdx.x*256 + threadIdx.x;   // < M_*N
  const int m = idx / N;
  const int n = idx - m*N;
  float a = 0.f;
  for (int s = 0; s < S; ++s) a += P[((size_t)s*M_ + m)*N + n];
  if (bias) a += bias[n];
  if (gelu) a = 0.5f*a*(1.0f + erff(a*0.70710678118654752f));
  if (res) a += res[idx];
  if (outA) outA[idx] = a;
  if (outT) outT[(size_t)n*M_ + m] = a;
  if (outB) outB[idx] = a;
}

// ================= attention scores + per-split softmax
// grid (SP, H_, B_), block 256, dyn LDS chunk*8 floats.
// Q: [M_][D_] f32 row-major. Kc: [B][TPp][D_] f32. Kn: [M_][D_] f32 (new rows) or null.
// Pbuf: per (bh,sp): [chunk][8] exp-weights. ML: per (bh,sp): [16] = {max[8] | sum[8]}.
__global__ __launch_bounds__(256) void attn_score(
    const float* __restrict__ Q, const float* __restrict__ Kc, const float* __restrict__ Kn,
    const float* __restrict__ mask,
    float* __restrict__ Pbuf, float* __restrict__ ML,
    int TK, int TPp, int chunk)
{
  extern __shared__ float sc[];                 // [chunk][8]
  const int tid = threadIdx.x;
  const int sp = blockIdx.x, h = blockIdx.y, b = blockIdx.z;
  const int SP = gridDim.x;
  const int j0 = sp * chunk;
  const int cnt = min(chunk, TK - j0);
  const int bh = b*H_ + h;
  float* Pp = Pbuf + ((size_t)bh*SP + sp)*chunk*8;

  for (int jl = tid; jl < cnt; jl += 256) {
    const int j = j0 + jl;
    float acc[8] = {0.f,0.f,0.f,0.f,0.f,0.f,0.f,0.f};
#pragma unroll
    for (int dc = 0; dc < 8; ++dc) {
      float4 k1, k2;
      if (j < TPp) {
        const float* kr = Kc + ((size_t)b*TPp + j)*D_ + h*DH_ + dc*8;
        k1 = *(const float4*)kr;
        k2 = *(const float4*)(kr + 4);
      } else {
        const float* kr = Kn + ((size_t)(b*TQ_ + (j - TPp)))*D_ + h*DH_ + dc*8;
        k1 = *(const float4*)kr;
        k2 = *(const float4*)(kr + 4);
      }
#pragma unroll
      for (int i = 0; i < 8; ++i) {
        const float* qp = Q + ((size_t)(b*TQ_ + i))*D_ + h*DH_ + dc*8;
        const float4 qa = *(const float4*)qp;
        const float4 qb = *(const float4*)(qp + 4);
        acc[i] += qa.x*k1.x+qa.y*k1.y+qa.z*k1.z+qa.w*k1.w
                + qb.x*k2.x+qb.y*k2.y+qb.z*k2.z+qb.w*k2.w;
      }
    }
#pragma unroll
    for (int i = 0; i < 8; ++i) {
      float vv = acc[i]*0.125f;       // (dh^-0.25)^2 on the q.k product
      if (mask) vv += mask[(size_t)i*TK + j];
      sc[jl*8 + i] = vv;
    }
  }
  __syncthreads();

  // 8 row-groups x 32 lanes
  const int g = tid >> 5, l = tid & 31;
  float mx = -3.0e38f;
  for (int jl = l; jl < cnt; jl += 32) mx = fmaxf(mx, sc[jl*8 + g]);
#pragma unroll
  for (int o = 16; o; o >>= 1) mx = fmaxf(mx, __shfl_down(mx, o, 32));
  mx = __shfl(mx, 0, 32);
  float sum = 0.f;
  for (int jl = l; jl < cnt; jl += 32) {
    const float e = __expf(sc[jl*8 + g] - mx);
    Pp[jl*8 + g] = e;
    sum += e;
  }
#pragma unroll
  for (int o = 16; o; o >>= 1) sum += __shfl_down(sum, o, 32);
  if (l == 0) {
    ML[((size_t)bh*SP + sp)*16 + g]     = mx;
    ML[((size_t)bh*SP + sp)*16 + 8 + g] = sum;
  }
}

// ================= PV + split-softmax merge; outT f32 [D_][M_]
// grid (H_, B_), block 256. Wave wv -> rows 2wv,2wv+1; lane -> d.
__global__ __launch_bounds__(256) void attn_pv(
    const float* __restrict__ Vc, const float* __restrict__ Vn,
    const float* __restrict__ Pbuf, const float* __restrict__ ML,
    float* __restrict__ outT, int TK, int TPp, int chunk, int SP)
{
  const int tid = threadIdx.x;
  const int h = blockIdx.x, b = blockIdx.y;
  const int bh = b*H_ + h;
  const int wv = tid >> 6, d = tid & 63;
  const int i0 = wv*2, i1 = i0 + 1;

  float M0 = -3.0e38f, M1 = -3.0e38f;
  for (int s = 0; s < SP; ++s) {
    M0 = fmaxf(M0, ML[((size_t)bh*SP + s)*16 + i0]);
    M1 = fmaxf(M1, ML[((size_t)bh*SP + s)*16 + i1]);
  }
  float L0 = 0.f, L1 = 0.f, a0 = 0.f, a1 = 0.f;
  for (int s = 0; s < SP; ++s) {
    const float w0 = __expf(ML[((size_t)bh*SP + s)*16 + i0] - M0);
    const float w1 = __expf(ML[((size_t)bh*SP + s)*16 + i1] - M1);
    L0 += w0 * ML[((size_t)bh*SP + s)*16 + 8 + i0];
    L1 += w1 * ML[((size_t)bh*SP + s)*16 + 8 + i1];
    const int jb = s*chunk;
    const int cnt = min(chunk, TK - jb);
    const float* Pp = Pbuf + ((size_t)bh*SP + s)*chunk*8;
    float s0 = 0.f, s1 = 0.f;
    for (int jl = 0; jl < cnt; ++jl) {
      const int j = jb + jl;
      const float vv = (j < TPp)
        ? Vc[((size_t)b*TPp + j)*D_ + h*DH_ + d]
        : Vn[((size_t)(b*TQ_ + (j - TPp)))*D_ + h*DH_ + d];
      const float2 p = *(const float2*)(Pp + jl*8 + i0);
      s0 += p.x*vv;
      s1 += p.y*vv;
    }
    a0 += w0*s0;
    a1 += w1*s1;
  }
  outT[((size_t)(h*DH_ + d))*M_ + b*TQ_ + i0] = a0 / L0;
  outT[((size_t)(h*DH_ + d))*M_ + b*TQ_ + i1] = a1 / L1;
}

extern "C" void kernel_launch(void* const* d_in, const int* in_sizes, int n_in,
                              void* d_out, int out_size, void* d_ws, size_t ws_size,
                              hipStream_t stream)
{
  (void)in_sizes; (void)n_in; (void)out_size; (void)ws_size;
  const float* x    = (const float*)d_in[0];
  const float* skc  = (const float*)d_in[1];
  const float* svc  = (const float*)d_in[2];
  const float* ck   = (const float*)d_in[3];
  const float* cv   = (const float*)d_in[4];
  const float* msk  = (const float*)d_in[5];
  const float* wq   = (const float*)d_in[6];
  const float* bq   = (const float*)d_in[7];
  const float* wk   = (const float*)d_in[8];
  const float* wvv  = (const float*)d_in[9];
  const float* bv   = (const float*)d_in[10];
  const float* wo   = (const float*)d_in[11];
  const float* bo   = (const float*)d_in[12];
  const float* cwq  = (const float*)d_in[13];
  const float* cbq  = (const float*)d_in[14];
  const float* cwo  = (const float*)d_in[15];
  const float* cbo  = (const float*)d_in[16];
  const float* ln1w = (const float*)d_in[17];
  const float* ln1b = (const float*)d_in[18];
  const float* ln2w = (const float*)d_in[19];
  const float* ln2b = (const float*)d_in[20];
  const float* ln3w = (const float*)d_in[21];
  const float* ln3b = (const float*)d_in[22];
  const float* w1   = (const float*)d_in[23];
  const float* b1   = (const float*)d_in[24];
  const float* w2   = (const float*)d_in[25];
  const float* b2   = (const float*)d_in[26];
  // d_in[27] = offset (int) — fixed at TP_ here.

  float* out_x  = (float*)d_out;
  float* out_k1 = out_x + 81920;
  float* out_v1 = out_x + 163840;

  float* ws = (float*)d_ws;           // 6,702,080 floats = 26.8 MB
  float* xlT  = ws + 0;               // [1280][64], reused 3x
  float* qbuf = ws + 81920;           // q / qc row-major [64][1280]
  float* k1f  = ws + 163840;
  float* v1f  = ws + 245760;
  float* x2   = ws + 327680;
  float* x3   = ws + 409600;
  float* attT = ws + 491520;          // attn out transposed, reused 2x
  float* hT   = ws + 573440;          // [5120][64]
  float* Pg   = ws + 901120;          // 3,276,800 floats of split-K partials
  float* Pq   = Pg;
  float* Pk   = Pg + 819200;
  float* Pv   = Pg + 1638400;
  float* PbS  = ws + 4177920;         // 160*4*114*8
  float* PbC  = ws + 4761600;         // 160*4*375*8
  float* MLS  = ws + 6681600;
  float* MLC  = ws + 6691840;

  const dim3 blk(256);

  // --- self-attention ---
  ln_kernel<<<dim3(64), blk, 0, stream>>>(x, ln1w, ln1b, xlT);
  gemm_splitk<<<dim3(10,10,3), blk, 0, stream>>>(xlT, wq, wk, wvv, Pq, Pk, Pv, 1280, 128);
  epilogue_kernel<<<dim3(320), blk, 0, stream>>>(Pq, 10, 1280, bq, nullptr, 0, qbuf, nullptr, nullptr);
  epilogue_kernel<<<dim3(320), blk, 0, stream>>>(Pk, 10, 1280, nullptr, nullptr, 0, k1f, nullptr, out_k1);
  epilogue_kernel<<<dim3(320), blk, 0, stream>>>(Pv, 10, 1280, bv, nullptr, 0, v1f, nullptr, out_v1);
  attn_score<<<dim3(4,20,8), blk, 114*8*4, stream>>>(qbuf, skc, k1f, msk, PbS, MLS, 455, 447, 114);
  attn_pv<<<dim3(20,8), blk, 0, stream>>>(svc, v1f, PbS, MLS, attT, 455, 447, 114, 4);
  gemm_splitk<<<dim3(10,10,1), blk, 0, stream>>>(attT, wo, wo, wo, Pq, Pq, Pq, 1280, 128);
  epilogue_kernel<<<dim3(320), blk, 0, stream>>>(Pq, 10, 1280, bo, x, 0, x2, nullptr, nullptr);

  // --- cross-attention ---
  ln_kernel<<<dim3(64), blk, 0, stream>>>(x2, ln2w, ln2b, xlT);
  gemm_splitk<<<dim3(10,10,1), blk, 0, stream>>>(xlT, cwq, cwq, cwq, Pq, Pq, Pq, 1280, 128);
  epilogue_kernel<<<dim3(320), blk, 0, stream>>>(Pq, 10, 1280, cbq, nullptr, 0, qbuf, nullptr, nullptr);
  attn_score<<<dim3(4,20,8), blk, 375*8*4, stream>>>(qbuf, ck, nullptr, nullptr, PbC, MLC, 1500, 1500, 375);
  attn_pv<<<dim3(20,8), blk, 0, stream>>>(cv, nullptr, PbC, MLC, attT, 1500, 1500, 375, 4);
  gemm_splitk<<<dim3(10,10,1), blk, 0, stream>>>(attT, cwo, cwo, cwo, Pq, Pq, Pq, 1280, 128);
  epilogue_kernel<<<dim3(320), blk, 0, stream>>>(Pq, 10, 1280, cbo, x2, 0, x3, nullptr, nullptr);

  // --- MLP ---
  ln_kernel<<<dim3(64), blk, 0, stream>>>(x3, ln3w, ln3b, xlT);
  gemm_splitk<<<dim3(40,10,1), blk, 0, stream>>>(xlT, w1, w1, w1, Pg, Pg, Pg, 5120, 128);
  epilogue_kernel<<<dim3(1280), blk, 0, stream>>>(Pg, 10, 5120, b1, nullptr, 1, nullptr, hT, nullptr);
  gemm_splitk<<<dim3(10,40,1), blk, 0, stream>>>(hT, w2, w2, w2, Pg, Pg, Pg, 1280, 128);
  epilogue_kernel<<<dim3(320), blk, 0, stream>>>(Pg, 40, 1280, b2, x3, 0, nullptr, nullptr, out_x);
}

// Round 4
// 696.336 us; speedup vs baseline: 2.0524x; 2.0524x over previous
//
#include <hip/hip_runtime.h>
#include <hip/hip_bf16.h>

#define B_   8
#define TQ_  8
#define TP_  447
#define TC_  1500
#define D_   1280
#define H_   20
#define DH_  64
#define DFF_ 5120
#define M_   64    // B_*TQ_ total rows

// ================= LayerNorm: row-major fp32 input -> transposed f32 [D_][M_]
__global__ __launch_bounds__(256) void ln_kernel(const float* __restrict__ X,
    const float* __restrict__ g, const float* __restrict__ be, float* __restrict__ outT)
{
  __shared__ float redA[4], redB[4];
  const int m = blockIdx.x;
  const int tid = threadIdx.x;
  float v[5];
#pragma unroll
  for (int t = 0; t < 5; ++t) v[t] = X[(size_t)m*D_ + tid + t*256];
  float s = v[0]+v[1]+v[2]+v[3]+v[4];
#pragma unroll
  for (int o = 32; o; o >>= 1) s += __shfl_down(s, o, 64);
  if ((tid & 63) == 0) redA[tid >> 6] = s;
  __syncthreads();
  const float mean = (redA[0]+redA[1]+redA[2]+redA[3]) * (1.0f/D_);
  float q = 0.f;
#pragma unroll
  for (int t = 0; t < 5; ++t) { const float d = v[t]-mean; q += d*d; }
#pragma unroll
  for (int o = 32; o; o >>= 1) q += __shfl_down(q, o, 64);
  if ((tid & 63) == 0) redB[tid >> 6] = q;
  __syncthreads();
  const float rstd = rsqrtf((redB[0]+redB[1]+redB[2]+redB[3]) * (1.0f/D_) + 1e-5f);
#pragma unroll
  for (int t = 0; t < 5; ++t) {
    const int c = tid + t*256;
    outT[(size_t)c*M_ + m] = (v[t]-mean)*rstd*g[c] + be[c];
  }
}

// ================= split-K GEMM: P[s][m][n] = sum_{k in chunk s} XT[k][m]*W[k][n]
__global__ __launch_bounds__(256) void gemm_splitk(
    const float* __restrict__ XT,
    const float* __restrict__ Wa, const float* __restrict__ Wb, const float* __restrict__ Wc,
    float* __restrict__ Pa, float* __restrict__ Pb, float* __restrict__ Pc,
    int N, int chunk)
{
  __shared__ float xs[64][64];
  const int z = blockIdx.z;
  const float* W = (z == 0 ? Wa : (z == 1 ? Wb : Wc));
  float* P = (z == 0 ? Pa : (z == 1 ? Pb : Pc));
  const int tid  = threadIdx.x;
  const int lane = tid & 63;
  const int wv   = tid >> 6;
  const int n    = blockIdx.x*128 + lane*2;
  const int k0   = blockIdx.y * chunk;
  float accL[16], accH[16];
#pragma unroll
  for (int r = 0; r < 16; ++r) { accL[r] = 0.f; accH[r] = 0.f; }

  for (int kb = 0; kb < chunk; kb += 64) {
    __syncthreads();
    {
      const float4* src = (const float4*)(XT + (size_t)(k0 + kb)*M_);
      float4* dst = (float4*)&xs[0][0];
#pragma unroll
      for (int i = 0; i < 4; ++i) dst[tid + i*256] = src[tid + i*256];
    }
    __syncthreads();
    const float* Wp = W + (size_t)(k0 + kb)*N + n;
    for (int kk = 0; kk < 64; ++kk) {
      const float2 wp = *(const float2*)(Wp + (size_t)kk*N);
      const float wl = wp.x;
      const float wh = wp.y;
      const float* xr = &xs[kk][wv*16];
#pragma unroll
      for (int r4 = 0; r4 < 4; ++r4) {
        const float4 xv = *(const float4*)(xr + r4*4);
        accL[r4*4+0] += xv.x*wl; accH[r4*4+0] += xv.x*wh;
        accL[r4*4+1] += xv.y*wl; accH[r4*4+1] += xv.y*wh;
        accL[r4*4+2] += xv.z*wl; accH[r4*4+2] += xv.z*wh;
        accL[r4*4+3] += xv.w*wl; accH[r4*4+3] += xv.w*wh;
      }
    }
  }
#pragma unroll
  for (int r = 0; r < 16; ++r) {
    const int m = wv*16 + r;
    float2 st; st.x = accL[r]; st.y = accH[r];
    *(float2*)(P + ((size_t)blockIdx.y*M_ + m)*N + n) = st;
  }
}

// ================= epilogue: sum split-K partials, +bias, gelu, +residual, multi-format out
__global__ __launch_bounds__(256) void epilogue_kernel(
    const float* __restrict__ P, int S, int N,
    const float* __restrict__ bias,
    const float* __restrict__ res,
    int gelu,
    float* __restrict__ outA, float* __restrict__ outT, float* __restrict__ outB)
{
  const int idx = blockIdx.x*256 + threadIdx.x;   // < M_*N
  const int m = idx / N;
  const int n = idx - m*N;
  float a = 0.f;
  for (int s = 0; s < S; ++s) a += P[((size_t)s*M_ + m)*N + n];
  if (bias) a += bias[n];
  if (gelu) a = 0.5f*a*(1.0f + erff(a*0.70710678118654752f));
  if (res) a += res[idx];
  if (outA) outA[idx] = a;
  if (outT) outT[(size_t)n*M_ + m] = a;
  if (outB) outB[idx] = a;
}

// ================= attention scores + per-split softmax
// grid (SP, H_, B_), block 256, dyn LDS chunk*8 floats.
__global__ __launch_bounds__(256) void attn_score(
    const float* __restrict__ Q, const float* __restrict__ Kc, const float* __restrict__ Kn,
    const float* __restrict__ mask,
    float* __restrict__ Pbuf, float* __restrict__ ML,
    int TK, int TPp, int chunk)
{
  extern __shared__ float sc[];                 // [chunk][8]
  const int tid = threadIdx.x;
  const int sp = blockIdx.x, h = blockIdx.y, b = blockIdx.z;
  const int SP = gridDim.x;
  const int j0 = sp * chunk;
  const int cnt = min(chunk, TK - j0);
  const int bh = b*H_ + h;
  float* Pp = Pbuf + ((size_t)bh*SP + sp)*chunk*8;

  for (int jl = tid; jl < cnt; jl += 256) {
    const int j = j0 + jl;
    float acc[8] = {0.f,0.f,0.f,0.f,0.f,0.f,0.f,0.f};
#pragma unroll
    for (int dc = 0; dc < 8; ++dc) {
      float4 k1, k2;
      if (j < TPp) {
        const float* kr = Kc + ((size_t)b*TPp + j)*D_ + h*DH_ + dc*8;
        k1 = *(const float4*)kr;
        k2 = *(const float4*)(kr + 4);
      } else {
        const float* kr = Kn + ((size_t)(b*TQ_ + (j - TPp)))*D_ + h*DH_ + dc*8;
        k1 = *(const float4*)kr;
        k2 = *(const float4*)(kr + 4);
      }
#pragma unroll
      for (int i = 0; i < 8; ++i) {
        const float* qp = Q + ((size_t)(b*TQ_ + i))*D_ + h*DH_ + dc*8;
        const float4 qa = *(const float4*)qp;
        const float4 qb = *(const float4*)(qp + 4);
        acc[i] += qa.x*k1.x+qa.y*k1.y+qa.z*k1.z+qa.w*k1.w
                + qb.x*k2.x+qb.y*k2.y+qb.z*k2.z+qb.w*k2.w;
      }
    }
#pragma unroll
    for (int i = 0; i < 8; ++i) {
      float vv = acc[i]*0.125f;       // (dh^-0.25)^2 on the q.k product
      if (mask) vv += mask[(size_t)i*TK + j];
      sc[jl*8 + i] = vv;
    }
  }
  __syncthreads();

  const int g = tid >> 5, l = tid & 31;
  float mx = -3.0e38f;
  for (int jl = l; jl < cnt; jl += 32) mx = fmaxf(mx, sc[jl*8 + g]);
#pragma unroll
  for (int o = 16; o; o >>= 1) mx = fmaxf(mx, __shfl_down(mx, o, 32));
  mx = __shfl(mx, 0, 32);
  float sum = 0.f;
  for (int jl = l; jl < cnt; jl += 32) {
    const float e = __expf(sc[jl*8 + g] - mx);
    Pp[jl*8 + g] = e;
    sum += e;
  }
#pragma unroll
  for (int o = 16; o; o >>= 1) sum += __shfl_down(sum, o, 32);
  if (l == 0) {
    ML[((size_t)bh*SP + sp)*16 + g]     = mx;
    ML[((size_t)bh*SP + sp)*16 + 8 + g] = sum;
  }
}

// ================= PV partials: grid (SP*SUB, H_, B_), block 256.
// Each block reduces a sub-chunk of one score-split; no softmax scaling yet.
// Opart: per (bh, spv): [8][64].
__global__ __launch_bounds__(256) void attn_pv_partial(
    const float* __restrict__ Vc, const float* __restrict__ Vn,
    const float* __restrict__ Pbuf, float* __restrict__ Opart,
    int TK, int TPp, int chunk, int SUB)
{
  const int tid = threadIdx.x;
  const int spv = blockIdx.x;
  const int SPV = gridDim.x;
  const int SP  = SPV / SUB;
  const int s   = spv / SUB;
  const int sub = spv - s*SUB;
  const int h = blockIdx.y, b = blockIdx.z;
  const int bh = b*H_ + h;
  const int subchunk = (chunk + SUB - 1) / SUB;
  const int jlb = sub * subchunk;
  const int cnt_split = min(chunk, TK - s*chunk);
  const int jle = min(jlb + subchunk, cnt_split);
  const int wv = tid >> 6, d = tid & 63;
  const int i0 = wv*2;
  const float* Pp = Pbuf + ((size_t)bh*SP + s)*chunk*8;
  float a0 = 0.f, a1 = 0.f;
  for (int jl = jlb; jl < jle; ++jl) {
    const int j = s*chunk + jl;
    const float vv = (j < TPp)
      ? Vc[((size_t)b*TPp + j)*D_ + h*DH_ + d]
      : Vn[((size_t)(b*TQ_ + (j - TPp)))*D_ + h*DH_ + d];
    const float2 p = *(const float2*)(Pp + jl*8 + i0);
    a0 += p.x*vv;
    a1 += p.y*vv;
  }
  Opart[(((size_t)bh*SPV + spv)*8 + i0    )*64 + d] = a0;
  Opart[(((size_t)bh*SPV + spv)*8 + i0 + 1)*64 + d] = a1;
}

// ================= merge PV partials with split-softmax weights; outT f32 [D_][M_]
__global__ __launch_bounds__(256) void attn_pv_combine(
    const float* __restrict__ Opart, const float* __restrict__ ML,
    float* __restrict__ outT, int SP, int SUB)
{
  const int tid = threadIdx.x;
  const int h = blockIdx.x, b = blockIdx.y;
  const int bh = b*H_ + h;
  const int SPV = SP*SUB;
  const int wv = tid >> 6, d = tid & 63;
  const int i0 = wv*2, i1 = i0 + 1;
  float M0 = -3.0e38f, M1 = -3.0e38f;
  for (int s = 0; s < SP; ++s) {
    M0 = fmaxf(M0, ML[((size_t)bh*SP + s)*16 + i0]);
    M1 = fmaxf(M1, ML[((size_t)bh*SP + s)*16 + i1]);
  }
  float L0 = 0.f, L1 = 0.f, o0 = 0.f, o1 = 0.f;
  for (int s = 0; s < SP; ++s) {
    const float w0 = __expf(ML[((size_t)bh*SP + s)*16 + i0] - M0);
    const float w1 = __expf(ML[((size_t)bh*SP + s)*16 + i1] - M1);
    L0 += w0 * ML[((size_t)bh*SP + s)*16 + 8 + i0];
    L1 += w1 * ML[((size_t)bh*SP + s)*16 + 8 + i1];
    for (int sub = 0; sub < SUB; ++sub) {
      const int spv = s*SUB + sub;
      o0 += w0 * Opart[(((size_t)bh*SPV + spv)*8 + i0)*64 + d];
      o1 += w1 * Opart[(((size_t)bh*SPV + spv)*8 + i1)*64 + d];
    }
  }
  outT[((size_t)(h*DH_ + d))*M_ + b*TQ_ + i0] = o0 / L0;
  outT[((size_t)(h*DH_ + d))*M_ + b*TQ_ + i1] = o1 / L1;
}

extern "C" void kernel_launch(void* const* d_in, const int* in_sizes, int n_in,
                              void* d_out, int out_size, void* d_ws, size_t ws_size,
                              hipStream_t stream)
{
  (void)in_sizes; (void)n_in; (void)out_size; (void)ws_size;
  const float* x    = (const float*)d_in[0];
  const float* skc  = (const float*)d_in[1];
  const float* svc  = (const float*)d_in[2];
  const float* ck   = (const float*)d_in[3];
  const float* cv   = (const float*)d_in[4];
  const float* msk  = (const float*)d_in[5];
  const float* wq   = (const float*)d_in[6];
  const float* bq   = (const float*)d_in[7];
  const float* wk   = (const float*)d_in[8];
  const float* wvv  = (const float*)d_in[9];
  const float* bv   = (const float*)d_in[10];
  const float* wo   = (const float*)d_in[11];
  const float* bo   = (const float*)d_in[12];
  const float* cwq  = (const float*)d_in[13];
  const float* cbq  = (const float*)d_in[14];
  const float* cwo  = (const float*)d_in[15];
  const float* cbo  = (const float*)d_in[16];
  const float* ln1w = (const float*)d_in[17];
  const float* ln1b = (const float*)d_in[18];
  const float* ln2w = (const float*)d_in[19];
  const float* ln2b = (const float*)d_in[20];
  const float* ln3w = (const float*)d_in[21];
  const float* ln3b = (const float*)d_in[22];
  const float* w1   = (const float*)d_in[23];
  const float* b1   = (const float*)d_in[24];
  const float* w2   = (const float*)d_in[25];
  const float* b2   = (const float*)d_in[26];
  // d_in[27] = offset (int) — fixed at TP_ here.

  float* out_x  = (float*)d_out;
  float* out_k1 = out_x + 81920;
  float* out_v1 = out_x + 163840;

  float* ws = (float*)d_ws;           // 6,702,080 floats = 26.8 MB
  float* xlT  = ws + 0;               // [1280][64], reused 3x
  float* qbuf = ws + 81920;           // q / qc row-major [64][1280]
  float* k1f  = ws + 163840;
  float* v1f  = ws + 245760;
  float* x2   = ws + 327680;
  float* x3   = ws + 409600;
  float* attT = ws + 491520;          // attn out transposed, reused 2x
  float* hT   = ws + 573440;          // [5120][64]
  float* Pg   = ws + 901120;          // 3,276,800 floats of split-K partials / PV partials
  float* Pq   = Pg;
  float* Pk   = Pg + 819200;
  float* Pv   = Pg + 1638400;
  float* PbS  = ws + 4177920;         // 160*4*114*8
  float* PbC  = ws + 4761600;         // 160*4*375*8
  float* MLS  = ws + 6681600;
  float* MLC  = ws + 6691840;

  const dim3 blk(256);

  // --- self-attention ---
  ln_kernel<<<dim3(64), blk, 0, stream>>>(x, ln1w, ln1b, xlT);
  gemm_splitk<<<dim3(10,10,3), blk, 0, stream>>>(xlT, wq, wk, wvv, Pq, Pk, Pv, 1280, 128);
  epilogue_kernel<<<dim3(320), blk, 0, stream>>>(Pq, 10, 1280, bq, nullptr, 0, qbuf, nullptr, nullptr);
  epilogue_kernel<<<dim3(320), blk, 0, stream>>>(Pk, 10, 1280, nullptr, nullptr, 0, k1f, nullptr, out_k1);
  epilogue_kernel<<<dim3(320), blk, 0, stream>>>(Pv, 10, 1280, bv, nullptr, 0, v1f, nullptr, out_v1);
  attn_score<<<dim3(4,20,8), blk, 114*8*4, stream>>>(qbuf, skc, k1f, msk, PbS, MLS, 455, 447, 114);
  attn_pv_partial<<<dim3(8,20,8), blk, 0, stream>>>(svc, v1f, PbS, Pg, 455, 447, 114, 2);
  attn_pv_combine<<<dim3(20,8), blk, 0, stream>>>(Pg, MLS, attT, 4, 2);
  gemm_splitk<<<dim3(10,10,1), blk, 0, stream>>>(attT, wo, wo, wo, Pq, Pq, Pq, 1280, 128);
  epilogue_kernel<<<dim3(320), blk, 0, stream>>>(Pq, 10, 1280, bo, x, 0, x2, nullptr, nullptr);

  // --- cross-attention ---
  ln_kernel<<<dim3(64), blk, 0, stream>>>(x2, ln2w, ln2b, xlT);
  gemm_splitk<<<dim3(10,10,1), blk, 0, stream>>>(xlT, cwq, cwq, cwq, Pq, Pq, Pq, 1280, 128);
  epilogue_kernel<<<dim3(320), blk, 0, stream>>>(Pq, 10, 1280, cbq, nullptr, 0, qbuf, nullptr, nullptr);
  attn_score<<<dim3(4,20,8), blk, 375*8*4, stream>>>(qbuf, ck, nullptr, nullptr, PbC, MLC, 1500, 1500, 375);
  attn_pv_partial<<<dim3(32,20,8), blk, 0, stream>>>(cv, nullptr, PbC, Pg, 1500, 1500, 375, 8);
  attn_pv_combine<<<dim3(20,8), blk, 0, stream>>>(Pg, MLC, attT, 4, 8);
  gemm_splitk<<<dim3(10,10,1), blk, 0, stream>>>(attT, cwo, cwo, cwo, Pq, Pq, Pq, 1280, 128);
  epilogue_kernel<<<dim3(320), blk, 0, stream>>>(Pq, 10, 1280, cbo, x2, 0, x3, nullptr, nullptr);

  // --- MLP ---
  ln_kernel<<<dim3(64), blk, 0, stream>>>(x3, ln3w, ln3b, xlT);
  gemm_splitk<<<dim3(40,10,1), blk, 0, stream>>>(xlT, w1, w1, w1, Pg, Pg, Pg, 5120, 128);
  epilogue_kernel<<<dim3(1280), blk, 0, stream>>>(Pg, 10, 5120, b1, nullptr, 1, nullptr, hT, nullptr);
  gemm_splitk<<<dim3(10,40,1), blk, 0, stream>>>(hT, w2, w2, w2, Pg, Pg, Pg, 1280, 128);
  epilogue_kernel<<<dim3(320), blk, 0, stream>>>(Pg, 40, 1280, b2, x3, 0, nullptr, nullptr, out_x);
}